// Round 17
// baseline (705.226 us; speedup 1.0000x reference)
//
#include <hip/hip_runtime.h>
#include <stdint.h>

typedef unsigned short u16;
typedef __attribute__((ext_vector_type(8))) short short8;
typedef __attribute__((ext_vector_type(4))) float f32x4;
typedef __attribute__((ext_vector_type(16))) float f32x16;
typedef __attribute__((ext_vector_type(4))) u16 u16x4;

// Problem constants: B=2, S=2048, H=4096, NH=32, NKV=8, HD=128, N_REP=4
static constexpr float SCALE = 0.08838834764831845f;        // 128^-0.5
static constexpr float QSCALE = 0.12752459769642898f;       // SCALE * log2(e)

__device__ __forceinline__ u16 f2bf(float f) {
    union { float f; unsigned u; } x; x.f = f;
    unsigned r = x.u + 0x7fffu + ((x.u >> 16) & 1u); // RNE
    return (u16)(r >> 16);
}
__device__ __forceinline__ float bf2f(u16 b) {
    union { unsigned u; float f; } x; x.u = ((unsigned)b) << 16;
    return x.f;
}
__device__ __forceinline__ unsigned cvt_pk_bf16(float lo, float hi_) {
    unsigned r;
    asm("v_cvt_pk_bf16_f32 %0, %1, %2" : "=v"(r) : "v"(lo), "v"(hi_));
    return r;
}

// ---------------- fused f32 -> bf16 convert for all 5 tensors ----------------
__global__ __launch_bounds__(256) void convert5_kernel(const float* __restrict__ s0, const float* __restrict__ s1,
                                                       const float* __restrict__ s2, const float* __restrict__ s3,
                                                       const float* __restrict__ s4,
                                                       u16* __restrict__ d0, u16* __restrict__ d1,
                                                       u16* __restrict__ d2, u16* __restrict__ d3,
                                                       u16* __restrict__ d4) {
    // float4 unit boundaries: hs 4M | Wq 4M | Wk 1M | Wv 1M | Wo 4M
    const int V0 = 4194304, V1 = 8388608, V2 = 9437184, V3 = 10485760, V4 = 14680064;
    const int stride = gridDim.x * blockDim.x;
    for (int i = blockIdx.x * blockDim.x + threadIdx.x; i < V4; i += stride) {
        const float* sp; u16* dp; int off;
        if (i < V0)      { sp = s0; dp = d0; off = i; }
        else if (i < V1) { sp = s1; dp = d1; off = i - V0; }
        else if (i < V2) { sp = s2; dp = d2; off = i - V1; }
        else if (i < V3) { sp = s3; dp = d3; off = i - V2; }
        else             { sp = s4; dp = d4; off = i - V3; }
        float4 v = *reinterpret_cast<const float4*>(sp + (size_t)off * 4);
        u16x4 o;
        o.x = f2bf(v.x); o.y = f2bf(v.y); o.z = f2bf(v.z); o.w = f2bf(v.w);
        *reinterpret_cast<u16x4*>(dp + (size_t)off * 4) = o;
    }
}

// ---------------- fused K+V projection GEMM (128^2 m97 structure, 512 blocks = 2/CU) ----------------
__global__ __launch_bounds__(256) void gemm_kv(const u16* __restrict__ A,
                                               const u16* __restrict__ Bk,
                                               const u16* __restrict__ Bv,
                                               u16* __restrict__ Ck,
                                               u16* __restrict__ Cvt) {
    constexpr int K = 4096, N = 1024, BK = 64;
    __shared__ u16 sA[128 * BK];
    __shared__ u16 sB[128 * BK];
    const int tid = threadIdx.x;
    const int wid = tid >> 6, lane = tid & 63;
    const int lrow = lane & 15, lgrp = lane >> 4;

    int bid = blockIdx.x;
    { const int cpx = 512 >> 3; bid = (bid & 7) * cpx + (bid >> 3); }   // bijective XCD swizzle
    const bool isV = bid >= 256;
    const int b2 = bid & 255;
    const int row0 = (b2 >> 3) * 128, col0 = (b2 & 7) * 128;
    const u16* __restrict__ B = isV ? Bv : Bk;
    const int wr = (wid >> 1) * 64, wc = (wid & 1) * 64;

    f32x4 acc[4][4] = {};

    const int NT = K / BK;
    for (int kt = 0; kt < NT; ++kt) {
        const int k0 = kt * BK;
        __syncthreads();
        #pragma unroll
        for (int rnd = 0; rnd < 4; ++rnd) {
            const int eoff = (rnd * 256 + tid) * 8;
            const int r = eoff >> 6, c = eoff & 63;
            const int gc = c ^ ((r & 7) << 3);
            const int ldsoff = rnd * 2048 + wid * 512;
            __builtin_amdgcn_global_load_lds(
                (const __attribute__((address_space(1))) void*)(A + (size_t)(row0 + r) * K + k0 + gc),
                (__attribute__((address_space(3))) void*)(&sA[ldsoff]), 16, 0, 0);
            __builtin_amdgcn_global_load_lds(
                (const __attribute__((address_space(1))) void*)(B + (size_t)(col0 + r) * K + k0 + gc),
                (__attribute__((address_space(3))) void*)(&sB[ldsoff]), 16, 0, 0);
        }
        __syncthreads();
        #pragma unroll
        for (int kk = 0; kk < 2; ++kk) {
            const int koff = kk * 32 + lgrp * 8;
            short8 af[4], bfr[4];
            #pragma unroll
            for (int m = 0; m < 4; ++m) {
                const int rr = wr + m * 16 + lrow;
                af[m] = *(const short8*)&sA[rr * BK + (koff ^ ((rr & 7) << 3))];
            }
            #pragma unroll
            for (int n = 0; n < 4; ++n) {
                const int rr = wc + n * 16 + lrow;
                bfr[n] = *(const short8*)&sB[rr * BK + (koff ^ ((rr & 7) << 3))];
            }
            #pragma unroll
            for (int m = 0; m < 4; ++m)
                #pragma unroll
                for (int n = 0; n < 4; ++n)
                    acc[m][n] = __builtin_amdgcn_mfma_f32_16x16x32_bf16(af[m], bfr[n], acc[m][n], 0, 0, 0);
        }
    }

    const int orow = row0 + wr + lgrp * 4;
    const int ocol = col0 + wc + lrow;
    if (!isV) {
        #pragma unroll
        for (int m = 0; m < 4; ++m)
            #pragma unroll
            for (int n = 0; n < 4; ++n)
                #pragma unroll
                for (int r = 0; r < 4; ++r)
                    Ck[(size_t)(orow + m * 16 + r) * N + ocol + n * 16] = f2bf(acc[m][n][r]);
    } else {
        #pragma unroll
        for (int m = 0; m < 4; ++m)
            #pragma unroll
            for (int n = 0; n < 4; ++n) {
                u16x4 pk;
                pk.x = f2bf(acc[m][n][0]); pk.y = f2bf(acc[m][n][1]);
                pk.z = f2bf(acc[m][n][2]); pk.w = f2bf(acc[m][n][3]);
                *(u16x4*)&Cvt[(size_t)(ocol + n * 16) * 4096 + orow + m * 16] = pk;
            }
    }
}

// ---------------- GEMM 256^2 v5 (R15-proven: ~147us, MfmaUtil ~40%) ----------------
template<int OUT_MODE>
__global__ __launch_bounds__(512, 1) void gemm256v5(const u16* __restrict__ A,
                                                    const u16* __restrict__ B,
                                                    void* __restrict__ Cv,
                                                    int M, int N, int K) {
    __shared__ u16 sA[2][2][256 * 32];   // 64 KiB
    __shared__ u16 sB[2][2][256 * 32];   // 64 KiB
    const int tid = threadIdx.x;
    const int wid = tid >> 6, lane = tid & 63;
    const int lrow = lane & 15, lgrp = lane >> 4;

    const int nbn = N >> 8;
    const int total = (M >> 8) * nbn;
    int bid = blockIdx.x;
    if ((total & 7) == 0) { const int cpx = total >> 3; bid = (bid & 7) * cpx + (bid >> 3); }
    const int row0 = (bid / nbn) * 256, col0 = (bid % nbn) * 256;
    const int wr = (wid >> 2) * 128, wc = (wid & 3) * 64;   // 2x4 waves, 128x64 out each

    f32x4 acc[8][4] = {};

    const int rS0 = wid * 32 + (lane >> 2);   // staging row (+g*16)
    const int uS = lane & 3;                  // phys 16B unit within 64B row

    auto stageA = [&](int nb, int kt, int kkh) {
        const int k0 = kt * 64 + kkh * 32;
        #pragma unroll
        for (int g = 0; g < 2; ++g) {
            const int r = rS0 + g * 16;
            const int cs = k0 + ((uS ^ ((r >> 1) & 3)) << 3);   // inverse swizzle on source
            __builtin_amdgcn_global_load_lds(
                (const __attribute__((address_space(1))) void*)(A + (size_t)(row0 + r) * K + cs),
                (__attribute__((address_space(3))) void*)(&sA[nb][kkh][(wid * 32 + g * 16) * 32]), 16, 0, 0);
        }
    };
    auto stageB = [&](int nb, int kt, int kkh) {
        const int k0 = kt * 64 + kkh * 32;
        #pragma unroll
        for (int g = 0; g < 2; ++g) {
            const int r = rS0 + g * 16;
            const int cs = k0 + ((uS ^ ((r >> 1) & 3)) << 3);
            __builtin_amdgcn_global_load_lds(
                (const __attribute__((address_space(1))) void*)(B + (size_t)(col0 + r) * K + cs),
                (__attribute__((address_space(3))) void*)(&sB[nb][kkh][(wid * 32 + g * 16) * 32]), 16, 0, 0);
        }
    };

    auto rdA = [&](int buf, int kkh, int fr) -> short8 {
        const int r = wr + fr * 16 + lrow;
        return *(const short8*)&sA[buf][kkh][r * 32 + ((lgrp ^ ((r >> 1) & 3)) << 3)];
    };
    auto rdB = [&](int buf, int kkh, int fc) -> short8 {
        const int r = wc + fc * 16 + lrow;
        return *(const short8*)&sB[buf][kkh][r * 32 + ((lgrp ^ ((r >> 1) & 3)) << 3)];
    };

    const int NK = K >> 6;    // BK = 64
    stageA(0, 0, 0); stageB(0, 0, 0); stageA(0, 0, 1); stageB(0, 0, 1);
    asm volatile("s_waitcnt vmcnt(4)" ::: "memory");
    __builtin_amdgcn_s_barrier();
    __builtin_amdgcn_sched_barrier(0);

    short8 a0[4], b0[4], a1[4], a2[4], b1[4], a3[4];
    #pragma unroll
    for (int fr = 0; fr < 4; ++fr) a0[fr] = rdA(0, 0, fr);
    #pragma unroll
    for (int fc = 0; fc < 4; ++fc) b0[fc] = rdB(0, 0, fc);
    __builtin_amdgcn_sched_barrier(0);

    for (int kt = 0; kt < NK; ++kt) {
        const int buf = kt & 1, nb = buf ^ 1;
        const bool st = (kt + 1 < NK);

        // ---- phase 1 ----
        #pragma unroll
        for (int fr = 0; fr < 4; ++fr) a1[fr] = rdA(buf, 0, fr + 4);
        if (st) stageA(nb, kt + 1, 0);
        asm volatile("s_waitcnt lgkmcnt(4)" ::: "memory");
        __builtin_amdgcn_sched_barrier(0);
        __builtin_amdgcn_s_setprio(1);
        #pragma unroll
        for (int fr = 0; fr < 4; ++fr)
            #pragma unroll
            for (int fc = 0; fc < 4; ++fc)
                acc[fr][fc] = __builtin_amdgcn_mfma_f32_16x16x32_bf16(a0[fr], b0[fc], acc[fr][fc], 0, 0, 0);
        __builtin_amdgcn_s_setprio(0);
        __builtin_amdgcn_sched_barrier(0);

        // ---- phase 2 ----
        if (st) stageB(nb, kt + 1, 0);
        asm volatile("s_waitcnt lgkmcnt(0)" ::: "memory");
        __builtin_amdgcn_sched_barrier(0);
        if (st) { asm volatile("s_waitcnt vmcnt(4)" ::: "memory"); }
        else    { asm volatile("s_waitcnt vmcnt(0)" ::: "memory"); }
        __builtin_amdgcn_s_barrier();
        __builtin_amdgcn_sched_barrier(0);
        #pragma unroll
        for (int fr = 0; fr < 4; ++fr) a2[fr] = rdA(buf, 1, fr);
        #pragma unroll
        for (int fc = 0; fc < 4; ++fc) b1[fc] = rdB(buf, 1, fc);
        __builtin_amdgcn_sched_barrier(0);
        __builtin_amdgcn_s_setprio(1);
        #pragma unroll
        for (int fr = 0; fr < 4; ++fr)
            #pragma unroll
            for (int fc = 0; fc < 4; ++fc)
                acc[fr + 4][fc] = __builtin_amdgcn_mfma_f32_16x16x32_bf16(a1[fr], b0[fc], acc[fr + 4][fc], 0, 0, 0);
        __builtin_amdgcn_s_setprio(0);
        __builtin_amdgcn_sched_barrier(0);

        // ---- phase 3 ----
        #pragma unroll
        for (int fr = 0; fr < 4; ++fr) a3[fr] = rdA(buf, 1, fr + 4);
        if (st) stageA(nb, kt + 1, 1);
        asm volatile("s_waitcnt lgkmcnt(4)" ::: "memory");
        __builtin_amdgcn_sched_barrier(0);
        __builtin_amdgcn_s_setprio(1);
        #pragma unroll
        for (int fr = 0; fr < 4; ++fr)
            #pragma unroll
            for (int fc = 0; fc < 4; ++fc)
                acc[fr][fc] = __builtin_amdgcn_mfma_f32_16x16x32_bf16(a2[fr], b1[fc], acc[fr][fc], 0, 0, 0);
        __builtin_amdgcn_s_setprio(0);
        __builtin_amdgcn_sched_barrier(0);

        // ---- phase 4 ----
        if (st) stageB(nb, kt + 1, 1);
        asm volatile("s_waitcnt lgkmcnt(0)" ::: "memory");
        __builtin_amdgcn_sched_barrier(0);
        if (st) { asm volatile("s_waitcnt vmcnt(4)" ::: "memory"); }
        __builtin_amdgcn_s_barrier();
        __builtin_amdgcn_sched_barrier(0);
        if (st) {
            #pragma unroll
            for (int fr = 0; fr < 4; ++fr) a0[fr] = rdA(nb, 0, fr);
            #pragma unroll
            for (int fc = 0; fc < 4; ++fc) b0[fc] = rdB(nb, 0, fc);
        }
        __builtin_amdgcn_sched_barrier(0);
        __builtin_amdgcn_s_setprio(1);
        #pragma unroll
        for (int fr = 0; fr < 4; ++fr)
            #pragma unroll
            for (int fc = 0; fc < 4; ++fc)
                acc[fr + 4][fc] = __builtin_amdgcn_mfma_f32_16x16x32_bf16(a3[fr], b1[fc], acc[fr + 4][fc], 0, 0, 0);
        __builtin_amdgcn_s_setprio(0);
        __builtin_amdgcn_sched_barrier(0);
    }

    const int orow = row0 + wr + lgrp * 4;
    const int ocol = col0 + wc + lrow;
    if (OUT_MODE == 2) {
        float* C = (float*)Cv;
        #pragma unroll
        for (int m = 0; m < 8; ++m)
            #pragma unroll
            for (int n = 0; n < 4; ++n)
                #pragma unroll
                for (int r = 0; r < 4; ++r)
                    C[(size_t)(orow + m * 16 + r) * N + ocol + n * 16] = acc[m][n][r];
    } else {
        u16* C = (u16*)Cv;
        #pragma unroll
        for (int m = 0; m < 8; ++m)
            #pragma unroll
            for (int n = 0; n < 4; ++n)
                #pragma unroll
                for (int r = 0; r < 4; ++r)
                    C[(size_t)(orow + m * 16 + r) * N + ocol + n * 16] = f2bf(acc[m][n][r]);
    }
}

// ---------------- RoPE (in-place, K only) ----------------
template<int NHEADS>
__global__ __launch_bounds__(256) void rope_kernel(u16* __restrict__ X,
                                                   const float* __restrict__ cosb,
                                                   const float* __restrict__ sinb,
                                                   float scale) {
    constexpr int LH = (NHEADS == 32) ? 5 : 3;
    const int total = 2 * 2048 * NHEADS * 64;
    const int stride = gridDim.x * blockDim.x;
    for (int i = blockIdx.x * blockDim.x + threadIdx.x; i < total; i += stride) {
        const int d = i & 63;
        const int h = (i >> 6) & (NHEADS - 1);
        const int rs = i >> (6 + LH);
        const size_t base = (size_t)rs * (NHEADS * 128) + h * 128 + d;
        const float c = cosb[rs * 128 + d] * scale;
        const float sn = sinb[rs * 128 + d] * scale;
        const float x1 = bf2f(X[base]);
        const float x2 = bf2f(X[base + 64]);
        X[base] = f2bf(x1 * c - x2 * sn);
        X[base + 64] = f2bf(x2 * c + x1 * sn);
    }
}

// ---------------- flash attention v2: NO LDS staging, K/V direct from L1/L2 ----------------
// m169 lesson (Common-mistake #7): per-(b,hkv) K/V panels are L1/L2-resident (per-tile
// footprint 16KB K + 16KB V; all 8 waves share one (b,h)) -> LDS staging + dbuf + per-tile
// __syncthreads was pure overhead coupling 8 waves. This kernel has NO barriers in the
// tile loop: each wave runs an independent pipeline; skipped causal tiles skip loads too.
// gg block decode (R10-proven pairing) kept.
__global__ __launch_bounds__(512, 2) void attn_kernel(const u16* __restrict__ Q,
                                                      const u16* __restrict__ K,
                                                      const u16* __restrict__ Vt,
                                                      u16* __restrict__ AO,
                                                      const float* __restrict__ cosp,
                                                      const float* __restrict__ sinp) {
    const int tid = threadIdx.x;
    const int wid = tid >> 6, lane = tid & 63;
    const int l31 = lane & 31, hi = lane >> 5;

    const int gg = blockIdx.x >> 6;                // 0..7
    const int bx = (gg < 4) ? gg : 11 - gg;        // causal q-tile index (complementary i/i+256)
    const int rem = blockIdx.x & 63;
    const int h = rem >> 1;
    const int b = rem & 1;
    const int hkv = h >> 2;
    const int rs0 = b * 2048;
    const int q0 = bx * 256;
    const int qw = q0 + wid * 32;
    const int q_lane = qw + l31;

    // Q fragments + in-register RoPE; QSCALE (softmax scale * log2e) folded in.
    short8 qf[8];
    {
        const u16* qb = Q + (size_t)(rs0 + q_lane) * 4096 + h * 128 + hi * 8;
        #pragma unroll
        for (int f = 0; f < 8; ++f) qf[f] = *(const short8*)(qb + f * 16);
        const float* cb = cosp + (size_t)(rs0 + q_lane) * 128 + hi * 8;
        const float* sb = sinp + (size_t)(rs0 + q_lane) * 128 + hi * 8;
        #pragma unroll
        for (int f = 0; f < 4; ++f) {
            float4 c0 = *(const float4*)(cb + f * 16);
            float4 c1 = *(const float4*)(cb + f * 16 + 4);
            float4 s0 = *(const float4*)(sb + f * 16);
            float4 s1 = *(const float4*)(sb + f * 16 + 4);
            const float cc[8] = {c0.x, c0.y, c0.z, c0.w, c1.x, c1.y, c1.z, c1.w};
            const float ss[8] = {s0.x, s0.y, s0.z, s0.w, s1.x, s1.y, s1.z, s1.w};
            #pragma unroll
            for (int jj = 0; jj < 8; ++jj) {
                const float x1 = bf2f((u16)qf[f][jj]);
                const float x2 = bf2f((u16)qf[f + 4][jj]);
                qf[f][jj]     = (short)f2bf((x1 * cc[jj] - x2 * ss[jj]) * QSCALE);
                qf[f + 4][jj] = (short)f2bf((x2 * cc[jj] + x1 * ss[jj]) * QSCALE);
            }
        }
    }

    f32x16 accO[4] = {};
    float m_c = -1e30f, l_c = 0.f;

    // per-lane base pointers (K rows / V^T rows for this lane)
    const u16* __restrict__ Kb0 = K + (size_t)(rs0 + l31) * 1024 + hkv * 128 + hi * 8;       // row l31
    const u16* __restrict__ Kb1 = K + (size_t)(rs0 + 32 + l31) * 1024 + hkv * 128 + hi * 8;  // row 32+l31
    const u16* __restrict__ Vb = Vt + (size_t)(hkv * 128 + l31) * 4096 + rs0 + hi * 8;       // V^T row l31 (+32*d4)

    const int NT = 4 * (bx + 1);
    for (int t = 0; t < NT; ++t) {
        const int kv0 = t * 64;
        if (kv0 > qw + 31) continue;   // wave-uniform causal skip (loads skipped too)

        // ---- QK^T (swapped): lane owns q-col l31; K rows direct from global (L1-hot) ----
        f32x16 sc[2] = {};
        #pragma unroll
        for (int f = 0; f < 8; ++f) {
            short8 k0 = *(const short8*)(Kb0 + (size_t)kv0 * 1024 + f * 16);
            short8 k1 = *(const short8*)(Kb1 + (size_t)kv0 * 1024 + f * 16);
            sc[0] = __builtin_amdgcn_mfma_f32_32x32x16_bf16(k0, qf[f], sc[0], 0, 0, 0);
            sc[1] = __builtin_amdgcn_mfma_f32_32x32x16_bf16(k1, qf[f], sc[1], 0, 0, 0);
        }

        if (kv0 + 63 > q_lane) {
            #pragma unroll
            for (int blk = 0; blk < 2; ++blk)
                #pragma unroll
                for (int r = 0; r < 16; ++r) {
                    const int kv_abs = kv0 + blk * 32 + ((r & 3) + 8 * (r >> 2) + 4 * hi);
                    if (kv_abs > q_lane) sc[blk][r] = -1e30f;
                }
        }

        float mx = sc[0][0];
        #pragma unroll
        for (int blk = 0; blk < 2; ++blk)
            #pragma unroll
            for (int r = 0; r < 16; ++r) mx = fmaxf(mx, sc[blk][r]);
        mx = fmaxf(mx, __shfl_xor(mx, 32));

        if (!__all(mx <= m_c + 8.0f)) {   // T13 defer-max
            const float sclf = __builtin_amdgcn_exp2f(m_c - mx);
            m_c = mx;
            l_c *= sclf;
            float sclq[16];
            #pragma unroll
            for (int r = 0; r < 16; ++r)
                sclq[r] = __shfl(sclf, (r & 3) + 8 * (r >> 2) + 4 * hi);
            #pragma unroll
            for (int d4 = 0; d4 < 4; ++d4)
                #pragma unroll
                for (int r = 0; r < 16; ++r) accO[d4][r] *= sclq[r];
        }
        float ssum = 0.f;
        #pragma unroll
        for (int blk = 0; blk < 2; ++blk)
            #pragma unroll
            for (int r = 0; r < 16; ++r) {
                const float p = __builtin_amdgcn_exp2f(sc[blk][r] - m_c);
                sc[blk][r] = p;
                ssum += p;
            }
        ssum += __shfl_xor(ssum, 32);
        l_c += ssum;

        // ---- PV: P->bf16 in-register (cvt_pk + cross-half shuffle); V^T direct from global ----
        #pragma unroll
        for (int blk = 0; blk < 2; ++blk) {
            #pragma unroll
            for (int tt = 0; tt < 2; ++tt) {
                const unsigned cv00 = cvt_pk_bf16(sc[blk][8 * tt + 0], sc[blk][8 * tt + 1]);
                const unsigned cv01 = cvt_pk_bf16(sc[blk][8 * tt + 2], sc[blk][8 * tt + 3]);
                const unsigned cv10 = cvt_pk_bf16(sc[blk][8 * tt + 4], sc[blk][8 * tt + 5]);
                const unsigned cv11 = cvt_pk_bf16(sc[blk][8 * tt + 6], sc[blk][8 * tt + 7]);
                const unsigned s00 = __shfl_xor(cv00, 32);
                const unsigned s01 = __shfl_xor(cv01, 32);
                const unsigned s10 = __shfl_xor(cv10, 32);
                const unsigned s11 = __shfl_xor(cv11, 32);
                union { unsigned w[4]; short8 v; } pa;
                pa.w[0] = hi ? s10 : cv00;
                pa.w[1] = hi ? s11 : cv01;
                pa.w[2] = hi ? cv10 : s00;
                pa.w[3] = hi ? cv11 : s01;
                const int kvc = kv0 + blk * 32 + tt * 16;   // hi*8 already in Vb
                #pragma unroll
                for (int d4 = 0; d4 < 4; ++d4) {
                    short8 vf = *(const short8*)(Vb + (size_t)(d4 * 32) * 4096 + kvc);
                    accO[d4] = __builtin_amdgcn_mfma_f32_32x32x16_bf16(pa.v, vf, accO[d4], 0, 0, 0);
                }
            }
        }
    }

    const float invl = 1.0f / l_c;
    float invq[16];
    #pragma unroll
    for (int r = 0; r < 16; ++r)
        invq[r] = __shfl(invl, (r & 3) + 8 * (r >> 2) + 4 * hi);
    #pragma unroll
    for (int d4 = 0; d4 < 4; ++d4)
        #pragma unroll
        for (int r = 0; r < 16; ++r) {
            const int q = qw + (r & 3) + 8 * (r >> 2) + 4 * hi;
            AO[(size_t)(rs0 + q) * 4096 + h * 128 + d4 * 32 + l31] = f2bf(accO[d4][r] * invq[r]);
        }
}

extern "C" void kernel_launch(void* const* d_in, const int* in_sizes, int n_in,
                              void* d_out, int out_size, void* d_ws, size_t ws_size,
                              hipStream_t stream) {
    const float* hs   = (const float*)d_in[0];
    const float* cosp = (const float*)d_in[1];
    const float* sinp = (const float*)d_in[2];
    // d_in[3] = attention_mask: exact causal -> implemented analytically
    const float* Wq = (const float*)d_in[4];
    const float* Wk = (const float*)d_in[5];
    const float* Wv = (const float*)d_in[6];
    const float* Wo = (const float*)d_in[7];

    u16* Xb = (u16*)d_out;              // 32 MiB (dead before O-proj overwrites)
    u16* Qb = (u16*)d_out + 16777216;   // 32 MiB
    char* w = (char*)d_ws;              // 128 MiB total
    u16* Wqb = (u16*)w; w += 33554432;
    u16* Wkb = (u16*)w; w += 8388608;
    u16* Wvb = (u16*)w; w += 8388608;
    u16* Wob = (u16*)w; w += 33554432;
    u16* Kb  = (u16*)w; w += 8388608;
    u16* Vtb = (u16*)w; w += 8388608;
    u16* AOb = (u16*)w; w += 33554432;

    convert5_kernel<<<4096, 256, 0, stream>>>(hs, Wq, Wk, Wv, Wo, Xb, Wqb, Wkb, Wvb, Wob);

    gemm256v5<0><<<256, 512, 0, stream>>>(Xb, Wqb, Qb, 4096, 4096, 4096);
    gemm_kv<<<512, 256, 0, stream>>>(Xb, Wkb, Wvb, Kb, Vtb);   // K+V fused, 2 blocks/CU

    rope_kernel<8><<<1024, 256, 0, stream>>>(Kb, cosp, sinp, 1.0f);  // K only; Q-rope is in attn

    attn_kernel<<<512, 512, 0, stream>>>(Qb, Kb, Vtb, AOb, cosp, sinp);

    gemm256v5<2><<<256, 512, 0, stream>>>(AOb, Wob, (float*)d_out, 4096, 4096, 4096);
}

// Round 18
// 498.130 us; speedup vs baseline: 1.4157x; 1.4157x over previous
//
#include <hip/hip_runtime.h>
#include <stdint.h>

typedef unsigned short u16;
typedef __attribute__((ext_vector_type(8))) short short8;
typedef __attribute__((ext_vector_type(4))) float f32x4;
typedef __attribute__((ext_vector_type(16))) float f32x16;
typedef __attribute__((ext_vector_type(4))) u16 u16x4;

// Problem constants: B=2, S=2048, H=4096, NH=32, NKV=8, HD=128, N_REP=4
static constexpr float SCALE = 0.08838834764831845f;        // 128^-0.5
static constexpr float QSCALE = 0.12752459769642898f;       // SCALE * log2(e)

__device__ __forceinline__ u16 f2bf(float f) {
    union { float f; unsigned u; } x; x.f = f;
    unsigned r = x.u + 0x7fffu + ((x.u >> 16) & 1u); // RNE
    return (u16)(r >> 16);
}
__device__ __forceinline__ float bf2f(u16 b) {
    union { unsigned u; float f; } x; x.u = ((unsigned)b) << 16;
    return x.f;
}
__device__ __forceinline__ unsigned cvt_pk_bf16(float lo, float hi_) {
    unsigned r;
    asm("v_cvt_pk_bf16_f32 %0, %1, %2" : "=v"(r) : "v"(lo), "v"(hi_));
    return r;
}

// ---------------- fused f32 -> bf16 convert for all 5 tensors ----------------
__global__ __launch_bounds__(256) void convert5_kernel(const float* __restrict__ s0, const float* __restrict__ s1,
                                                       const float* __restrict__ s2, const float* __restrict__ s3,
                                                       const float* __restrict__ s4,
                                                       u16* __restrict__ d0, u16* __restrict__ d1,
                                                       u16* __restrict__ d2, u16* __restrict__ d3,
                                                       u16* __restrict__ d4) {
    // float4 unit boundaries: hs 4M | Wq 4M | Wk 1M | Wv 1M | Wo 4M
    const int V0 = 4194304, V1 = 8388608, V2 = 9437184, V3 = 10485760, V4 = 14680064;
    const int stride = gridDim.x * blockDim.x;
    for (int i = blockIdx.x * blockDim.x + threadIdx.x; i < V4; i += stride) {
        const float* sp; u16* dp; int off;
        if (i < V0)      { sp = s0; dp = d0; off = i; }
        else if (i < V1) { sp = s1; dp = d1; off = i - V0; }
        else if (i < V2) { sp = s2; dp = d2; off = i - V1; }
        else if (i < V3) { sp = s3; dp = d3; off = i - V2; }
        else             { sp = s4; dp = d4; off = i - V3; }
        float4 v = *reinterpret_cast<const float4*>(sp + (size_t)off * 4);
        u16x4 o;
        o.x = f2bf(v.x); o.y = f2bf(v.y); o.z = f2bf(v.z); o.w = f2bf(v.w);
        *reinterpret_cast<u16x4*>(dp + (size_t)off * 4) = o;
    }
}

// ---------------- fused K+V projection GEMM (128^2 m97 structure, 512 blocks = 2/CU) ----------------
__global__ __launch_bounds__(256) void gemm_kv(const u16* __restrict__ A,
                                               const u16* __restrict__ Bk,
                                               const u16* __restrict__ Bv,
                                               u16* __restrict__ Ck,
                                               u16* __restrict__ Cvt) {
    constexpr int K = 4096, N = 1024, BK = 64;
    __shared__ u16 sA[128 * BK];
    __shared__ u16 sB[128 * BK];
    const int tid = threadIdx.x;
    const int wid = tid >> 6, lane = tid & 63;
    const int lrow = lane & 15, lgrp = lane >> 4;

    int bid = blockIdx.x;
    { const int cpx = 512 >> 3; bid = (bid & 7) * cpx + (bid >> 3); }   // bijective XCD swizzle
    const bool isV = bid >= 256;
    const int b2 = bid & 255;
    const int row0 = (b2 >> 3) * 128, col0 = (b2 & 7) * 128;
    const u16* __restrict__ B = isV ? Bv : Bk;
    const int wr = (wid >> 1) * 64, wc = (wid & 1) * 64;

    f32x4 acc[4][4] = {};

    const int NT = K / BK;
    for (int kt = 0; kt < NT; ++kt) {
        const int k0 = kt * BK;
        __syncthreads();
        #pragma unroll
        for (int rnd = 0; rnd < 4; ++rnd) {
            const int eoff = (rnd * 256 + tid) * 8;
            const int r = eoff >> 6, c = eoff & 63;
            const int gc = c ^ ((r & 7) << 3);
            const int ldsoff = rnd * 2048 + wid * 512;
            __builtin_amdgcn_global_load_lds(
                (const __attribute__((address_space(1))) void*)(A + (size_t)(row0 + r) * K + k0 + gc),
                (__attribute__((address_space(3))) void*)(&sA[ldsoff]), 16, 0, 0);
            __builtin_amdgcn_global_load_lds(
                (const __attribute__((address_space(1))) void*)(B + (size_t)(col0 + r) * K + k0 + gc),
                (__attribute__((address_space(3))) void*)(&sB[ldsoff]), 16, 0, 0);
        }
        __syncthreads();
        #pragma unroll
        for (int kk = 0; kk < 2; ++kk) {
            const int koff = kk * 32 + lgrp * 8;
            short8 af[4], bfr[4];
            #pragma unroll
            for (int m = 0; m < 4; ++m) {
                const int rr = wr + m * 16 + lrow;
                af[m] = *(const short8*)&sA[rr * BK + (koff ^ ((rr & 7) << 3))];
            }
            #pragma unroll
            for (int n = 0; n < 4; ++n) {
                const int rr = wc + n * 16 + lrow;
                bfr[n] = *(const short8*)&sB[rr * BK + (koff ^ ((rr & 7) << 3))];
            }
            #pragma unroll
            for (int m = 0; m < 4; ++m)
                #pragma unroll
                for (int n = 0; n < 4; ++n)
                    acc[m][n] = __builtin_amdgcn_mfma_f32_16x16x32_bf16(af[m], bfr[n], acc[m][n], 0, 0, 0);
        }
    }

    const int orow = row0 + wr + lgrp * 4;
    const int ocol = col0 + wc + lrow;
    if (!isV) {
        #pragma unroll
        for (int m = 0; m < 4; ++m)
            #pragma unroll
            for (int n = 0; n < 4; ++n)
                #pragma unroll
                for (int r = 0; r < 4; ++r)
                    Ck[(size_t)(orow + m * 16 + r) * N + ocol + n * 16] = f2bf(acc[m][n][r]);
    } else {
        #pragma unroll
        for (int m = 0; m < 4; ++m)
            #pragma unroll
            for (int n = 0; n < 4; ++n) {
                u16x4 pk;
                pk.x = f2bf(acc[m][n][0]); pk.y = f2bf(acc[m][n][1]);
                pk.z = f2bf(acc[m][n][2]); pk.w = f2bf(acc[m][n][3]);
                *(u16x4*)&Cvt[(size_t)(ocol + n * 16) * 4096 + orow + m * 16] = pk;
            }
    }
}

// ---------------- GEMM 256^2 v5 (R15-proven: ~147us, MfmaUtil ~40%) ----------------
template<int OUT_MODE>
__global__ __launch_bounds__(512, 1) void gemm256v5(const u16* __restrict__ A,
                                                    const u16* __restrict__ B,
                                                    void* __restrict__ Cv,
                                                    int M, int N, int K) {
    __shared__ u16 sA[2][2][256 * 32];   // 64 KiB
    __shared__ u16 sB[2][2][256 * 32];   // 64 KiB
    const int tid = threadIdx.x;
    const int wid = tid >> 6, lane = tid & 63;
    const int lrow = lane & 15, lgrp = lane >> 4;

    const int nbn = N >> 8;
    const int total = (M >> 8) * nbn;
    int bid = blockIdx.x;
    if ((total & 7) == 0) { const int cpx = total >> 3; bid = (bid & 7) * cpx + (bid >> 3); }
    const int row0 = (bid / nbn) * 256, col0 = (bid % nbn) * 256;
    const int wr = (wid >> 2) * 128, wc = (wid & 3) * 64;   // 2x4 waves, 128x64 out each

    f32x4 acc[8][4] = {};

    const int rS0 = wid * 32 + (lane >> 2);   // staging row (+g*16)
    const int uS = lane & 3;                  // phys 16B unit within 64B row

    auto stageA = [&](int nb, int kt, int kkh) {
        const int k0 = kt * 64 + kkh * 32;
        #pragma unroll
        for (int g = 0; g < 2; ++g) {
            const int r = rS0 + g * 16;
            const int cs = k0 + ((uS ^ ((r >> 1) & 3)) << 3);   // inverse swizzle on source
            __builtin_amdgcn_global_load_lds(
                (const __attribute__((address_space(1))) void*)(A + (size_t)(row0 + r) * K + cs),
                (__attribute__((address_space(3))) void*)(&sA[nb][kkh][(wid * 32 + g * 16) * 32]), 16, 0, 0);
        }
    };
    auto stageB = [&](int nb, int kt, int kkh) {
        const int k0 = kt * 64 + kkh * 32;
        #pragma unroll
        for (int g = 0; g < 2; ++g) {
            const int r = rS0 + g * 16;
            const int cs = k0 + ((uS ^ ((r >> 1) & 3)) << 3);
            __builtin_amdgcn_global_load_lds(
                (const __attribute__((address_space(1))) void*)(B + (size_t)(col0 + r) * K + cs),
                (__attribute__((address_space(3))) void*)(&sB[nb][kkh][(wid * 32 + g * 16) * 32]), 16, 0, 0);
        }
    };

    auto rdA = [&](int buf, int kkh, int fr) -> short8 {
        const int r = wr + fr * 16 + lrow;
        return *(const short8*)&sA[buf][kkh][r * 32 + ((lgrp ^ ((r >> 1) & 3)) << 3)];
    };
    auto rdB = [&](int buf, int kkh, int fc) -> short8 {
        const int r = wc + fc * 16 + lrow;
        return *(const short8*)&sB[buf][kkh][r * 32 + ((lgrp ^ ((r >> 1) & 3)) << 3)];
    };

    const int NK = K >> 6;    // BK = 64
    stageA(0, 0, 0); stageB(0, 0, 0); stageA(0, 0, 1); stageB(0, 0, 1);
    asm volatile("s_waitcnt vmcnt(4)" ::: "memory");
    __builtin_amdgcn_s_barrier();
    __builtin_amdgcn_sched_barrier(0);

    short8 a0[4], b0[4], a1[4], a2[4], b1[4], a3[4];
    #pragma unroll
    for (int fr = 0; fr < 4; ++fr) a0[fr] = rdA(0, 0, fr);
    #pragma unroll
    for (int fc = 0; fc < 4; ++fc) b0[fc] = rdB(0, 0, fc);
    __builtin_amdgcn_sched_barrier(0);

    for (int kt = 0; kt < NK; ++kt) {
        const int buf = kt & 1, nb = buf ^ 1;
        const bool st = (kt + 1 < NK);

        // ---- phase 1 ----
        #pragma unroll
        for (int fr = 0; fr < 4; ++fr) a1[fr] = rdA(buf, 0, fr + 4);
        if (st) stageA(nb, kt + 1, 0);
        asm volatile("s_waitcnt lgkmcnt(4)" ::: "memory");
        __builtin_amdgcn_sched_barrier(0);
        __builtin_amdgcn_s_setprio(1);
        #pragma unroll
        for (int fr = 0; fr < 4; ++fr)
            #pragma unroll
            for (int fc = 0; fc < 4; ++fc)
                acc[fr][fc] = __builtin_amdgcn_mfma_f32_16x16x32_bf16(a0[fr], b0[fc], acc[fr][fc], 0, 0, 0);
        __builtin_amdgcn_s_setprio(0);
        __builtin_amdgcn_sched_barrier(0);

        // ---- phase 2 ----
        if (st) stageB(nb, kt + 1, 0);
        asm volatile("s_waitcnt lgkmcnt(0)" ::: "memory");
        __builtin_amdgcn_sched_barrier(0);
        if (st) { asm volatile("s_waitcnt vmcnt(4)" ::: "memory"); }
        else    { asm volatile("s_waitcnt vmcnt(0)" ::: "memory"); }
        __builtin_amdgcn_s_barrier();
        __builtin_amdgcn_sched_barrier(0);
        #pragma unroll
        for (int fr = 0; fr < 4; ++fr) a2[fr] = rdA(buf, 1, fr);
        #pragma unroll
        for (int fc = 0; fc < 4; ++fc) b1[fc] = rdB(buf, 1, fc);
        __builtin_amdgcn_sched_barrier(0);
        __builtin_amdgcn_s_setprio(1);
        #pragma unroll
        for (int fr = 0; fr < 4; ++fr)
            #pragma unroll
            for (int fc = 0; fc < 4; ++fc)
                acc[fr + 4][fc] = __builtin_amdgcn_mfma_f32_16x16x32_bf16(a1[fr], b0[fc], acc[fr + 4][fc], 0, 0, 0);
        __builtin_amdgcn_s_setprio(0);
        __builtin_amdgcn_sched_barrier(0);

        // ---- phase 3 ----
        #pragma unroll
        for (int fr = 0; fr < 4; ++fr) a3[fr] = rdA(buf, 1, fr + 4);
        if (st) stageA(nb, kt + 1, 1);
        asm volatile("s_waitcnt lgkmcnt(4)" ::: "memory");
        __builtin_amdgcn_sched_barrier(0);
        __builtin_amdgcn_s_setprio(1);
        #pragma unroll
        for (int fr = 0; fr < 4; ++fr)
            #pragma unroll
            for (int fc = 0; fc < 4; ++fc)
                acc[fr][fc] = __builtin_amdgcn_mfma_f32_16x16x32_bf16(a2[fr], b1[fc], acc[fr][fc], 0, 0, 0);
        __builtin_amdgcn_s_setprio(0);
        __builtin_amdgcn_sched_barrier(0);

        // ---- phase 4 ----
        if (st) stageB(nb, kt + 1, 1);
        asm volatile("s_waitcnt lgkmcnt(0)" ::: "memory");
        __builtin_amdgcn_sched_barrier(0);
        if (st) { asm volatile("s_waitcnt vmcnt(4)" ::: "memory"); }
        __builtin_amdgcn_s_barrier();
        __builtin_amdgcn_sched_barrier(0);
        if (st) {
            #pragma unroll
            for (int fr = 0; fr < 4; ++fr) a0[fr] = rdA(nb, 0, fr);
            #pragma unroll
            for (int fc = 0; fc < 4; ++fc) b0[fc] = rdB(nb, 0, fc);
        }
        __builtin_amdgcn_sched_barrier(0);
        __builtin_amdgcn_s_setprio(1);
        #pragma unroll
        for (int fr = 0; fr < 4; ++fr)
            #pragma unroll
            for (int fc = 0; fc < 4; ++fc)
                acc[fr + 4][fc] = __builtin_amdgcn_mfma_f32_16x16x32_bf16(a3[fr], b1[fc], acc[fr + 4][fc], 0, 0, 0);
        __builtin_amdgcn_s_setprio(0);
        __builtin_amdgcn_sched_barrier(0);
    }

    const int orow = row0 + wr + lgrp * 4;
    const int ocol = col0 + wc + lrow;
    if (OUT_MODE == 2) {
        float* C = (float*)Cv;
        #pragma unroll
        for (int m = 0; m < 8; ++m)
            #pragma unroll
            for (int n = 0; n < 4; ++n)
                #pragma unroll
                for (int r = 0; r < 4; ++r)
                    C[(size_t)(orow + m * 16 + r) * N + ocol + n * 16] = acc[m][n][r];
    } else {
        u16* C = (u16*)Cv;
        #pragma unroll
        for (int m = 0; m < 8; ++m)
            #pragma unroll
            for (int n = 0; n < 4; ++n)
                #pragma unroll
                for (int r = 0; r < 4; ++r)
                    C[(size_t)(orow + m * 16 + r) * N + ocol + n * 16] = f2bf(acc[m][n][r]);
    }
}

// ---------------- RoPE (in-place, K only) ----------------
template<int NHEADS>
__global__ __launch_bounds__(256) void rope_kernel(u16* __restrict__ X,
                                                   const float* __restrict__ cosb,
                                                   const float* __restrict__ sinb,
                                                   float scale) {
    constexpr int LH = (NHEADS == 32) ? 5 : 3;
    const int total = 2 * 2048 * NHEADS * 64;
    const int stride = gridDim.x * blockDim.x;
    for (int i = blockIdx.x * blockDim.x + threadIdx.x; i < total; i += stride) {
        const int d = i & 63;
        const int h = (i >> 6) & (NHEADS - 1);
        const int rs = i >> (6 + LH);
        const size_t base = (size_t)rs * (NHEADS * 128) + h * 128 + d;
        const float c = cosb[rs * 128 + d] * scale;
        const float sn = sinb[rs * 128 + d] * scale;
        const float x1 = bf2f(X[base]);
        const float x2 = bf2f(X[base + 64]);
        X[base] = f2bf(x1 * c - x2 * sn);
        X[base + 64] = f2bf(x2 * c + x1 * sn);
    }
}

// ---------------- flash attention, 8-wave 32x32 swapped-QK^T; Q-RoPE+scale folded in-register ----------------
// Block decode (gg-mapping, R10-proven): with 512 blocks at 2/CU the dispatcher pairs
// block i with i+256 on one CU; bx(i)=i>>6 and bx(i+256)=7-(i>>6) give per-CU NT-sum = 36
// (balanced). Do NOT "fix" this pairing (R13 regression). Staged LDS K/V with
// global_load_lds prefetch is REQUIRED (R17: de-staging regressed 125->305us).
__global__ __launch_bounds__(512, 2) void attn_kernel(const u16* __restrict__ Q,
                                                      const u16* __restrict__ K,
                                                      const u16* __restrict__ Vt,
                                                      u16* __restrict__ AO,
                                                      const float* __restrict__ cosp,
                                                      const float* __restrict__ sinp) {
    __shared__ u16 sK[2][64 * 128];  // [kv][d], elem-col ^ ((row&15)<<3)
    __shared__ u16 sV[2][128 * 64];  // [d][kv], elem-col ^ ((row&7)<<3)
    const int tid = threadIdx.x;
    const int wid = tid >> 6, lane = tid & 63;
    const int l31 = lane & 31, hi = lane >> 5;

    const int gg = blockIdx.x >> 6;                // 0..7
    const int bx = (gg < 4) ? gg : 11 - gg;        // causal q-tile index (complementary i/i+256)
    const int rem = blockIdx.x & 63;
    const int h = rem >> 1;
    const int b = rem & 1;
    const int hkv = h >> 2;
    const int rs0 = b * 2048;
    const int q0 = bx * 256;
    const int qw = q0 + wid * 32;
    const int q_lane = qw + l31;

    // Q fragments + in-register RoPE; QSCALE (softmax scale * log2e) folded in.
    short8 qf[8];
    {
        const u16* qb = Q + (size_t)(rs0 + q_lane) * 4096 + h * 128 + hi * 8;
        #pragma unroll
        for (int f = 0; f < 8; ++f) qf[f] = *(const short8*)(qb + f * 16);
        const float* cb = cosp + (size_t)(rs0 + q_lane) * 128 + hi * 8;
        const float* sb = sinp + (size_t)(rs0 + q_lane) * 128 + hi * 8;
        #pragma unroll
        for (int f = 0; f < 4; ++f) {
            float4 c0 = *(const float4*)(cb + f * 16);
            float4 c1 = *(const float4*)(cb + f * 16 + 4);
            float4 s0 = *(const float4*)(sb + f * 16);
            float4 s1 = *(const float4*)(sb + f * 16 + 4);
            const float cc[8] = {c0.x, c0.y, c0.z, c0.w, c1.x, c1.y, c1.z, c1.w};
            const float ss[8] = {s0.x, s0.y, s0.z, s0.w, s1.x, s1.y, s1.z, s1.w};
            #pragma unroll
            for (int jj = 0; jj < 8; ++jj) {
                const float x1 = bf2f((u16)qf[f][jj]);
                const float x2 = bf2f((u16)qf[f + 4][jj]);
                qf[f][jj]     = (short)f2bf((x1 * cc[jj] - x2 * ss[jj]) * QSCALE);
                qf[f + 4][jj] = (short)f2bf((x2 * cc[jj] + x1 * ss[jj]) * QSCALE);
            }
        }
    }

    f32x16 accO[4] = {};
    float m_c = -1e30f, l_c = 0.f;

    auto stage = [&](int bf, int t) {
        const int kv0 = t * 64;
        #pragma unroll
        for (int rnd = 0; rnd < 2; ++rnd) {
            {
                const int e = rnd * 4096 + tid * 8;
                const int r = e >> 7, c = e & 127;
                const int cs = c ^ ((r & 15) << 3);
                __builtin_amdgcn_global_load_lds(
                    (const __attribute__((address_space(1))) void*)(K + (size_t)(rs0 + kv0 + r) * 1024 + hkv * 128 + cs),
                    (__attribute__((address_space(3))) void*)(&sK[bf][rnd * 4096 + wid * 512]), 16, 0, 0);
            }
            {
                const int e = rnd * 4096 + tid * 8;
                const int r = e >> 6, c = e & 63;
                const int cs = c ^ ((r & 7) << 3);
                __builtin_amdgcn_global_load_lds(
                    (const __attribute__((address_space(1))) void*)(Vt + (size_t)(hkv * 128 + r) * 4096 + rs0 + kv0 + cs),
                    (__attribute__((address_space(3))) void*)(&sV[bf][rnd * 4096 + wid * 512]), 16, 0, 0);
            }
        }
    };

    const int NT = 4 * (bx + 1);
    stage(0, 0);
    __syncthreads();
    int buf = 0;

    for (int t = 0; t < NT; ++t) {
        if (t + 1 < NT) stage(buf ^ 1, t + 1);
        const int kv0 = t * 64;

        if (kv0 <= qw + 31) {
            f32x16 sc[2] = {};
            #pragma unroll
            for (int f = 0; f < 8; ++f) {
                const int col = f * 16 + hi * 8;
                const int r0 = l31, r1 = 32 + l31;
                short8 k0 = *(const short8*)&sK[buf][r0 * 128 + (col ^ ((r0 & 15) << 3))];
                short8 k1 = *(const short8*)&sK[buf][r1 * 128 + (col ^ ((r1 & 15) << 3))];
                sc[0] = __builtin_amdgcn_mfma_f32_32x32x16_bf16(k0, qf[f], sc[0], 0, 0, 0);
                sc[1] = __builtin_amdgcn_mfma_f32_32x32x16_bf16(k1, qf[f], sc[1], 0, 0, 0);
            }

            if (kv0 + 63 > q_lane) {
                #pragma unroll
                for (int blk = 0; blk < 2; ++blk)
                    #pragma unroll
                    for (int r = 0; r < 16; ++r) {
                        const int kv_abs = kv0 + blk * 32 + ((r & 3) + 8 * (r >> 2) + 4 * hi);
                        if (kv_abs > q_lane) sc[blk][r] = -1e30f;
                    }
            }

            float mx = sc[0][0];
            #pragma unroll
            for (int blk = 0; blk < 2; ++blk)
                #pragma unroll
                for (int r = 0; r < 16; ++r) mx = fmaxf(mx, sc[blk][r]);
            mx = fmaxf(mx, __shfl_xor(mx, 32));

            if (!__all(mx <= m_c + 8.0f)) {
                const float sclf = __builtin_amdgcn_exp2f(m_c - mx);
                m_c = mx;
                l_c *= sclf;
                float sclq[16];
                #pragma unroll
                for (int r = 0; r < 16; ++r)
                    sclq[r] = __shfl(sclf, (r & 3) + 8 * (r >> 2) + 4 * hi);
                #pragma unroll
                for (int d4 = 0; d4 < 4; ++d4)
                    #pragma unroll
                    for (int r = 0; r < 16; ++r) accO[d4][r] *= sclq[r];
            }
            float ssum = 0.f;
            #pragma unroll
            for (int blk = 0; blk < 2; ++blk)
                #pragma unroll
                for (int r = 0; r < 16; ++r) {
                    const float p = __builtin_amdgcn_exp2f(sc[blk][r] - m_c);
                    sc[blk][r] = p;
                    ssum += p;
                }
            ssum += __shfl_xor(ssum, 32);
            l_c += ssum;

            #pragma unroll
            for (int blk = 0; blk < 2; ++blk) {
                #pragma unroll
                for (int tt = 0; tt < 2; ++tt) {
                    const unsigned cv00 = cvt_pk_bf16(sc[blk][8 * tt + 0], sc[blk][8 * tt + 1]);
                    const unsigned cv01 = cvt_pk_bf16(sc[blk][8 * tt + 2], sc[blk][8 * tt + 3]);
                    const unsigned cv10 = cvt_pk_bf16(sc[blk][8 * tt + 4], sc[blk][8 * tt + 5]);
                    const unsigned cv11 = cvt_pk_bf16(sc[blk][8 * tt + 6], sc[blk][8 * tt + 7]);
                    const unsigned s00 = __shfl_xor(cv00, 32);
                    const unsigned s01 = __shfl_xor(cv01, 32);
                    const unsigned s10 = __shfl_xor(cv10, 32);
                    const unsigned s11 = __shfl_xor(cv11, 32);
                    union { unsigned w[4]; short8 v; } pa;
                    pa.w[0] = hi ? s10 : cv00;
                    pa.w[1] = hi ? s11 : cv01;
                    pa.w[2] = hi ? cv10 : s00;
                    pa.w[3] = hi ? cv11 : s01;
                    const int kvb = blk * 32 + tt * 16 + hi * 8;
                    #pragma unroll
                    for (int d4 = 0; d4 < 4; ++d4) {
                        const int vr = d4 * 32 + l31;
                        short8 vf = *(const short8*)&sV[buf][vr * 64 + (kvb ^ ((vr & 7) << 3))];
                        accO[d4] = __builtin_amdgcn_mfma_f32_32x32x16_bf16(pa.v, vf, accO[d4], 0, 0, 0);
                    }
                }
            }
        }
        __syncthreads();
        buf ^= 1;
    }

    const float invl = 1.0f / l_c;
    float invq[16];
    #pragma unroll
    for (int r = 0; r < 16; ++r)
        invq[r] = __shfl(invl, (r & 3) + 8 * (r >> 2) + 4 * hi);
    #pragma unroll
    for (int d4 = 0; d4 < 4; ++d4)
        #pragma unroll
        for (int r = 0; r < 16; ++r) {
            const int q = qw + (r & 3) + 8 * (r >> 2) + 4 * hi;
            AO[(size_t)(rs0 + q) * 4096 + h * 128 + d4 * 32 + l31] = f2bf(accO[d4][r] * invq[r]);
        }
}

extern "C" void kernel_launch(void* const* d_in, const int* in_sizes, int n_in,
                              void* d_out, int out_size, void* d_ws, size_t ws_size,
                              hipStream_t stream) {
    const float* hs   = (const float*)d_in[0];
    const float* cosp = (const float*)d_in[1];
    const float* sinp = (const float*)d_in[2];
    // d_in[3] = attention_mask: exact causal -> implemented analytically
    const float* Wq = (const float*)d_in[4];
    const float* Wk = (const float*)d_in[5];
    const float* Wv = (const float*)d_in[6];
    const float* Wo = (const float*)d_in[7];

    u16* Xb = (u16*)d_out;              // 32 MiB (dead before O-proj overwrites)
    u16* Qb = (u16*)d_out + 16777216;   // 32 MiB
    char* w = (char*)d_ws;              // 128 MiB total
    u16* Wqb = (u16*)w; w += 33554432;
    u16* Wkb = (u16*)w; w += 8388608;
    u16* Wvb = (u16*)w; w += 8388608;
    u16* Wob = (u16*)w; w += 33554432;
    u16* Kb  = (u16*)w; w += 8388608;
    u16* Vtb = (u16*)w; w += 8388608;
    u16* AOb = (u16*)w; w += 33554432;

    convert5_kernel<<<4096, 256, 0, stream>>>(hs, Wq, Wk, Wv, Wo, Xb, Wqb, Wkb, Wvb, Wob);

    gemm256v5<0><<<256, 512, 0, stream>>>(Xb, Wqb, Qb, 4096, 4096, 4096);
    gemm_kv<<<512, 256, 0, stream>>>(Xb, Wkb, Wvb, Kb, Vtb);   // K+V fused, 2 blocks/CU

    rope_kernel<8><<<1024, 256, 0, stream>>>(Kb, cosp, sinp, 1.0f);  // K only; Q-rope is in attn

    attn_kernel<<<512, 512, 0, stream>>>(Qb, Kb, Vtb, AOb, cosp, sinp);

    gemm256v5<2><<<256, 512, 0, stream>>>(AOb, Wob, (float*)d_out, 4096, 4096, 4096);
}